// Round 3
// baseline (181.345 us; speedup 1.0000x reference)
//
#include <hip/hip_runtime.h>
#include <math.h>

#define N_RAYS 65536
#define LAMBDA_OPACITY 0.001f
#define LAMBDA_DISTORTION 0.001f

#define WAVES_PER_BLOCK 4
#define RAYS_PER_WAVE 4        // 16 lanes per ray
#define LANES_PER_RAY 16
#define SAMPLES_PER_LANE 12    // 16 lanes * 12 = 192 samples

// ---------------------------------------------------------------------------
// Distortion: 4 rays per 64-lane wave. Lane group g=lane>>4 owns ray 4W+g;
// sub-lane sl=lane&15 owns contiguous samples [12*sl, 12*sl+12).
// float4 loads; width-16 segmented scan (offsets 1,2,4,8 -> DPP-able).
// ---------------------------------------------------------------------------
__global__ __launch_bounds__(WAVES_PER_BLOCK * 64)
void distortion_kernel(
    const float* __restrict__ ws,
    const float* __restrict__ deltas,
    const float* __restrict__ ts,
    const int*   __restrict__ rays_a,
    float* __restrict__ out)
{
    const int wave = threadIdx.x >> 6;
    const int lane = threadIdx.x & 63;
    const int W    = blockIdx.x * WAVES_PER_BLOCK + wave;  // global wave id
    const int g    = lane >> 4;                            // ray slot in wave
    const int sl   = lane & 15;                            // sub-lane in ray
    const int ray  = W * RAYS_PER_WAVE + g;
    if (ray >= N_RAYS) return;   // grid sized exactly; kept for safety

    const int out_ray = rays_a[ray * 3 + 0];
    const int start   = rays_a[ray * 3 + 1];
    const int count   = rays_a[ray * 3 + 2];   // 192 in this setup

    const int s0 = sl * SAMPLES_PER_LANE;

    float w[SAMPLES_PER_LANE], t[SAMPLES_PER_LANE], d[SAMPLES_PER_LANE];

    if (s0 + SAMPLES_PER_LANE <= count && (((start + s0) & 3) == 0)) {
        // fully in-bounds, 16B-aligned: 3x float4 per array
        const float4* wp = (const float4*)(ws     + start + s0);
        const float4* tp = (const float4*)(ts     + start + s0);
        const float4* dp = (const float4*)(deltas + start + s0);
        #pragma unroll
        for (int q = 0; q < 3; ++q) {
            float4 vw = wp[q], vt = tp[q], vd = dp[q];
            w[4*q+0] = vw.x; w[4*q+1] = vw.y; w[4*q+2] = vw.z; w[4*q+3] = vw.w;
            t[4*q+0] = vt.x; t[4*q+1] = vt.y; t[4*q+2] = vt.z; t[4*q+3] = vt.w;
            d[4*q+0] = vd.x; d[4*q+1] = vd.y; d[4*q+2] = vd.z; d[4*q+3] = vd.w;
        }
    } else {
        #pragma unroll
        for (int k = 0; k < SAMPLES_PER_LANE; ++k) {
            const bool ok = (s0 + k) < count;
            const int  p  = start + s0 + k;
            w[k] = ok ? ws[p]     : 0.f;
            t[k] = ok ? ts[p]     : 0.f;
            d[k] = ok ? deltas[p] : 0.f;
        }
    }

    // lane totals
    float lw = 0.f, lwt = 0.f;
    #pragma unroll
    for (int k = 0; k < SAMPLES_PER_LANE; ++k) {
        lw  += w[k];
        lwt += w[k] * t[k];
    }

    // width-16 segmented inclusive scan of lane totals (offsets 1,2,4,8)
    float iw = lw, iwt = lwt;
    #pragma unroll
    for (int off = 1; off < LANES_PER_RAY; off <<= 1) {
        float nw  = __shfl_up(iw,  off, LANES_PER_RAY);
        float nwt = __shfl_up(iwt, off, LANES_PER_RAY);
        if (sl >= off) { iw += nw; iwt += nwt; }
    }

    // exclusive base for this lane's segment
    float e_w  = iw  - lw;
    float e_wt = iwt - lwt;

    // lane-local sequential exclusive accumulation over 12 samples
    float acc = 0.f;
    #pragma unroll
    for (int k = 0; k < SAMPLES_PER_LANE; ++k) {
        acc += 2.f * w[k] * (t[k] * e_w - e_wt) + w[k] * w[k] * d[k] * (1.f / 3.f);
        e_w  += w[k];
        e_wt += w[k] * t[k];
    }

    // width-16 reduction (offsets 8,4,2,1)
    #pragma unroll
    for (int off = LANES_PER_RAY / 2; off > 0; off >>= 1)
        acc += __shfl_down(acc, off, LANES_PER_RAY);

    if (sl == 0)
        out[3 * N_RAYS + out_ray] = LAMBDA_DISTORTION * acc;
}

// ---------------------------------------------------------------------------
// Per-ray cheap terms: 1 thread per ray, fully coalesced (~6 MB total).
// ---------------------------------------------------------------------------
__global__ __launch_bounds__(256)
void perray_kernel(
    const float* __restrict__ rgb_coarse,
    const float* __restrict__ rgb_fine,
    const float* __restrict__ rgb_target,
    const float* __restrict__ depth,
    const float* __restrict__ depth_target,
    const float* __restrict__ opacity,
    float* __restrict__ out)
{
    const int r = blockIdx.x * blockDim.x + threadIdx.x;
    if (r >= N_RAYS) return;

    const float rt0 = rgb_target[r * 3 + 0];
    const float rt1 = rgb_target[r * 3 + 1];
    const float rt2 = rgb_target[r * 3 + 2];
    const float c0 = rgb_coarse[r * 3 + 0] - rt0;
    const float c1 = rgb_coarse[r * 3 + 1] - rt1;
    const float c2 = rgb_coarse[r * 3 + 2] - rt2;
    const float f0 = rgb_fine[r * 3 + 0] - rt0;
    const float f1 = rgb_fine[r * 3 + 1] - rt1;
    const float f2 = rgb_fine[r * 3 + 2] - rt2;

    out[r] = (c0 * c0 + c1 * c1 + c2 * c2) * (1.f / 3.f)
           + (f0 * f0 + f1 * f1 + f2 * f2) * (1.f / 3.f);

    out[N_RAYS + r] = fabsf(depth[r] - depth_target[r]);

    const float o = opacity[r] + 1e-10f;
    out[2 * N_RAYS + r] = LAMBDA_OPACITY * (-o * logf(o));
}

extern "C" void kernel_launch(void* const* d_in, const int* in_sizes, int n_in,
                              void* d_out, int out_size, void* d_ws, size_t ws_size,
                              hipStream_t stream) {
    const float* rgb_coarse   = (const float*)d_in[0];
    const float* rgb_fine     = (const float*)d_in[1];
    const float* rgb_target   = (const float*)d_in[2];
    const float* depth        = (const float*)d_in[3];
    const float* depth_target = (const float*)d_in[4];
    const float* opacity      = (const float*)d_in[5];
    const float* ws           = (const float*)d_in[6];
    const float* deltas       = (const float*)d_in[7];
    const float* ts           = (const float*)d_in[8];
    const int*   rays_a       = (const int*)d_in[9];
    float* out = (float*)d_out;

    const int rays_per_block = WAVES_PER_BLOCK * RAYS_PER_WAVE;   // 16
    const int grid_d = (N_RAYS + rays_per_block - 1) / rays_per_block;
    distortion_kernel<<<grid_d, WAVES_PER_BLOCK * 64, 0, stream>>>(
        ws, deltas, ts, rays_a, out);

    perray_kernel<<<N_RAYS / 256, 256, 0, stream>>>(
        rgb_coarse, rgb_fine, rgb_target, depth, depth_target, opacity, out);
}

// Round 5
// 179.514 us; speedup vs baseline: 1.0102x; 1.0102x over previous
//
#include <hip/hip_runtime.h>
#include <math.h>

#define N_RAYS 65536
#define LAMBDA_OPACITY 0.001f
#define LAMBDA_DISTORTION 0.001f

// ---------------------------------------------------------------------------
// DPP wave64 inclusive-add scan (canonical gfx9 sequence, all-VALU):
//   x += row_shr:1; x += row_shr:2; x += row_shr:4; x += row_shr:8;
//   x += row_bcast:15 (rows 1,3); x += row_bcast:31 (rows 2,3)
// old=0 so masked/invalid lanes contribute 0 either way.
// ---------------------------------------------------------------------------
template <int CTRL, int ROW_MASK>
__device__ __forceinline__ float dpp_add(float x) {
    int s = __builtin_amdgcn_update_dpp(0, __float_as_int(x),
                                        CTRL, ROW_MASK, 0xf, false);
    return x + __int_as_float(s);
}

__device__ __forceinline__ float wave64_incl_scan(float x) {
    x = dpp_add<0x111, 0xf>(x);  // row_shr:1
    x = dpp_add<0x112, 0xf>(x);  // row_shr:2
    x = dpp_add<0x114, 0xf>(x);  // row_shr:4
    x = dpp_add<0x118, 0xf>(x);  // row_shr:8
    x = dpp_add<0x142, 0xa>(x);  // row_bcast:15 -> rows 1,3
    x = dpp_add<0x143, 0xc>(x);  // row_bcast:31 -> rows 2,3
    return x;
}

// ---------------------------------------------------------------------------
// Distortion: one 64-lane wave per ray. Lanes 0..47 each own one float4 quad
// (samples 4*lane .. 4*lane+3) -> 3 contiguous 768B load instructions per
// wave. Exclusive prefixes via one DPP scan over quad sums; ray totals land
// in lane 63, which does the single store.
// ---------------------------------------------------------------------------
__global__ __launch_bounds__(256)
void distortion_kernel(
    const float* __restrict__ ws,
    const float* __restrict__ deltas,
    const float* __restrict__ ts,
    const int*   __restrict__ rays_a,
    float* __restrict__ out)
{
    const int lane = threadIdx.x & 63;
    const int ray  = blockIdx.x * 4 + (threadIdx.x >> 6);
    if (ray >= N_RAYS) return;   // wave-uniform; grid sized exactly

    const int out_ray = rays_a[ray * 3 + 0];
    const int start   = rays_a[ray * 3 + 1];
    const int count   = rays_a[ray * 3 + 2];

    float w[4] = {0.f, 0.f, 0.f, 0.f};
    float t[4] = {0.f, 0.f, 0.f, 0.f};
    float d[4] = {0.f, 0.f, 0.f, 0.f};

    if (count == 192 && ((start & 3) == 0)) {
        // fast path: 48 quads cover the ray; lanes 48..63 carry zeros
        if (lane < 48) {
            const float4 vw = *(const float4*)(ws     + start + 4 * lane);
            const float4 vt = *(const float4*)(ts     + start + 4 * lane);
            const float4 vd = *(const float4*)(deltas + start + 4 * lane);
            __builtin_amdgcn_sched_barrier(0);  // keep all 3 loads in flight
            w[0] = vw.x; w[1] = vw.y; w[2] = vw.z; w[3] = vw.w;
            t[0] = vt.x; t[1] = vt.y; t[2] = vt.z; t[3] = vt.w;
            d[0] = vd.x; d[1] = vd.y; d[2] = vd.z; d[3] = vd.w;
        }
    } else {
        // generic path (any count <= 256, any alignment): guarded scalar loads
        #pragma unroll
        for (int e = 0; e < 4; ++e) {
            const int p  = 4 * lane + e;
            const bool ok = p < count;
            w[e] = ok ? ws[start + p]     : 0.f;
            t[e] = ok ? ts[start + p]     : 0.f;
            d[e] = ok ? deltas[start + p] : 0.f;
        }
    }

    // per-lane quad totals
    const float wt0 = w[0] * t[0], wt1 = w[1] * t[1];
    const float wt2 = w[2] * t[2], wt3 = w[3] * t[3];
    const float lw  = (w[0] + w[1]) + (w[2] + w[3]);
    const float lwt = (wt0 + wt1) + (wt2 + wt3);

    // DPP inclusive scans over quad totals (two independent chains)
    const float iw  = wave64_incl_scan(lw);
    const float iwt = wave64_incl_scan(lwt);

    // exclusive base for this quad
    float e_w  = iw  - lw;
    float e_wt = iwt - lwt;

    // lane-local sequential exclusive accumulation over the 4 samples
    float acc = 0.f;
    #pragma unroll
    for (int e = 0; e < 4; ++e) {
        acc += 2.f * w[e] * (t[e] * e_w - e_wt) + w[e] * w[e] * d[e] * (1.f / 3.f);
        e_w  += w[e];
        e_wt += w[e] * t[e];
    }

    // ray total via one more DPP scan; lane 63 holds the full sum
    const float tot = wave64_incl_scan(acc);
    if (lane == 63)
        out[3 * N_RAYS + out_ray] = LAMBDA_DISTORTION * tot;
}

// ---------------------------------------------------------------------------
// Per-ray cheap terms: 1 thread per ray, fully coalesced (~6 MB total).
// ---------------------------------------------------------------------------
__global__ __launch_bounds__(256)
void perray_kernel(
    const float* __restrict__ rgb_coarse,
    const float* __restrict__ rgb_fine,
    const float* __restrict__ rgb_target,
    const float* __restrict__ depth,
    const float* __restrict__ depth_target,
    const float* __restrict__ opacity,
    float* __restrict__ out)
{
    const int r = blockIdx.x * blockDim.x + threadIdx.x;
    if (r >= N_RAYS) return;

    const float rt0 = rgb_target[r * 3 + 0];
    const float rt1 = rgb_target[r * 3 + 1];
    const float rt2 = rgb_target[r * 3 + 2];
    const float c0 = rgb_coarse[r * 3 + 0] - rt0;
    const float c1 = rgb_coarse[r * 3 + 1] - rt1;
    const float c2 = rgb_coarse[r * 3 + 2] - rt2;
    const float f0 = rgb_fine[r * 3 + 0] - rt0;
    const float f1 = rgb_fine[r * 3 + 1] - rt1;
    const float f2 = rgb_fine[r * 3 + 2] - rt2;

    out[r] = (c0 * c0 + c1 * c1 + c2 * c2) * (1.f / 3.f)
           + (f0 * f0 + f1 * f1 + f2 * f2) * (1.f / 3.f);

    out[N_RAYS + r] = fabsf(depth[r] - depth_target[r]);

    const float o = opacity[r] + 1e-10f;
    out[2 * N_RAYS + r] = LAMBDA_OPACITY * (-o * logf(o));
}

extern "C" void kernel_launch(void* const* d_in, const int* in_sizes, int n_in,
                              void* d_out, int out_size, void* d_ws, size_t ws_size,
                              hipStream_t stream) {
    const float* rgb_coarse   = (const float*)d_in[0];
    const float* rgb_fine     = (const float*)d_in[1];
    const float* rgb_target   = (const float*)d_in[2];
    const float* depth        = (const float*)d_in[3];
    const float* depth_target = (const float*)d_in[4];
    const float* opacity      = (const float*)d_in[5];
    const float* ws           = (const float*)d_in[6];
    const float* deltas       = (const float*)d_in[7];
    const float* ts           = (const float*)d_in[8];
    const int*   rays_a       = (const int*)d_in[9];
    float* out = (float*)d_out;

    // 4 waves per block, 1 ray per wave
    distortion_kernel<<<N_RAYS / 4, 256, 0, stream>>>(
        ws, deltas, ts, rays_a, out);

    perray_kernel<<<N_RAYS / 256, 256, 0, stream>>>(
        rgb_coarse, rgb_fine, rgb_target, depth, depth_target, opacity, out);
}